// Round 5
// baseline (197.510 us; speedup 1.0000x reference)
//
#include <hip/hip_runtime.h>
#include <math.h>

// Cached SDPA decode: B=8 H=32 Q=1 D=128, MAX_SEQ=4096, fp32 in/out.
// R5: fully-fused single kernel. One block per bh (grid=256 = 1 block/CU),
// 1024 threads = 16 waves, each wave streams 256 keys with the 2-stage
// pipelined paired loop (lanes 0-31 = key s, lanes 32-63 = key s+1,
// float4/lane nontemporal loads). 32 half-wave partials combined in LDS;
// the new key/value (logical cache row cpos) merged as partial 33; output
// written directly. No workspace, no second dispatch.

#define BH_   256                 // B*H
#define D_    128
#define MAXS_ 4096
#define NW_   16                  // waves per block
#define KPW_  (MAXS_ / NW_)       // 256 keys per wave
#define NPART_ (NW_ * 2)          // 32 half-wave partials

typedef float f4n __attribute__((ext_vector_type(4)));

static __device__ __forceinline__ f4n ntld4(const float* p) {
    return __builtin_nontemporal_load((const f4n*)p);
}

__global__ __launch_bounds__(1024) void attn_fused_kernel(
    const float* __restrict__ q,
    const float* __restrict__ knew,
    const float* __restrict__ vnew,
    const float* __restrict__ ck,
    const float* __restrict__ cv,
    const int*   __restrict__ cpos_p,
    float*       __restrict__ out)
{
    const int bh   = blockIdx.x;         // 0..255
    const int wave = threadIdx.x >> 6;   // 0..15
    const int lane = threadIdx.x & 63;
    const int half = lane >> 5;          // which of the 2 keys per wave-load
    const int li   = lane & 31;          // dim-group owner within half

    const int cpos = cpos_p[0];          // hot loop covers cache rows [0,cpos)

    const float scale = 0.08838834764831845f;  // 1/sqrt(128)

    // lane owns dims 4*li..4*li+3 (same dims in both halves); scale folded in
    f4n qv = *(const f4n*)(q + (size_t)bh * D_ + li * 4);
    qv *= scale;

    const int base  = wave * KPW_;
    int limit = cpos - base;
    limit = limit < 0 ? 0 : (limit > KPW_ ? KPW_ : limit);

    float m = -INFINITY;
    float l = 0.0f;
    f4n   o = {0.0f, 0.0f, 0.0f, 0.0f};

    const float* __restrict__ kbase = ck + (size_t)bh * MAXS_ * D_;
    const float* __restrict__ vbase = cv + (size_t)bh * MAXS_ * D_;

#define UPDATE(KV, VV)                                                   \
    do {                                                                 \
        float dp = (KV).x * qv.x + (KV).y * qv.y                         \
                 + (KV).z * qv.z + (KV).w * qv.w;                        \
        dp += __shfl_xor(dp, 16);                                        \
        dp += __shfl_xor(dp, 8);                                         \
        dp += __shfl_xor(dp, 4);                                         \
        dp += __shfl_xor(dp, 2);                                         \
        dp += __shfl_xor(dp, 1);                                         \
        const float mn   = fmaxf(m, dp);                                 \
        const float corr = __expf(m - mn);                               \
        const float p    = __expf(dp - mn);                              \
        l   = l   * corr + p;                                            \
        o.x = o.x * corr + p * (VV).x;                                   \
        o.y = o.y * corr + p * (VV).y;                                   \
        o.z = o.z * corr + p * (VV).z;                                   \
        o.w = o.w * corr + p * (VV).w;                                   \
        m = mn;                                                          \
    } while (0)

    if (limit == KPW_) {
        // fast path: full 256-key tile, 2-stage pipeline (2 wave-loads ahead)
        const float* kp = kbase + (size_t)base * D_ + lane * 4;
        const float* vp = vbase + (size_t)base * D_ + lane * 4;
        f4n ka = ntld4(kp),        va = ntld4(vp);
        f4n kb = ntld4(kp + 256),  vb = ntld4(vp + 256);
        kp += 512; vp += 512;
        for (int i = 0; i < (KPW_ / 4) - 1; ++i) {   // 63 iterations
            const f4n kc = ntld4(kp),       vc = ntld4(vp);
            const f4n kd = ntld4(kp + 256), vd = ntld4(vp + 256);
            kp += 512; vp += 512;
            UPDATE(ka, va);
            UPDATE(kb, vb);
            ka = kc; va = vc; kb = kd; vb = vd;
        }
        UPDATE(ka, va);
        UPDATE(kb, vb);
    } else {
        // generic path: paired loop + odd tail (half 0 only)
        const int npairs = limit >> 1;
        for (int i = 0; i < npairs; ++i) {
            const int s0 = base + i * 2;
            const f4n kv = ntld4(kbase + (size_t)s0 * D_ + lane * 4);
            const f4n vv = ntld4(vbase + (size_t)s0 * D_ + lane * 4);
            UPDATE(kv, vv);
        }
        if ((limit & 1) && half == 0) {
            const int s = base + limit - 1;
            const f4n kv = ntld4(kbase + (size_t)s * D_ + li * 4);
            const f4n vv = ntld4(vbase + (size_t)s * D_ + li * 4);
            UPDATE(kv, vv);
        }
    }
#undef UPDATE

    // stash the 32 half-wave partials in LDS
    __shared__ float s_o[NPART_][D_];
    __shared__ float s_m[NPART_];
    __shared__ float s_l[NPART_];
    const int pi = wave * 2 + half;
    *(f4n*)&s_o[pi][li * 4] = o;
    if (li == 0) { s_m[pi] = m; s_l[pi] = l; }
    __syncthreads();

    // wave 0: merge 32 partials + the new key/value (logical row cpos),
    // normalize, write out.
    if (wave == 0) {
        // new-key score across the full wave (64 lanes x 2 dims)
        const float2 q2 = *(const float2*)(q    + (size_t)bh * D_ + lane * 2);
        const float2 k2 = *(const float2*)(knew + (size_t)bh * D_ + lane * 2);
        float dp = q2.x * k2.x + q2.y * k2.y;
        #pragma unroll
        for (int off = 32; off > 0; off >>= 1) dp += __shfl_xor(dp, off);
        const float sc = dp * scale;

        float M = sc;
        #pragma unroll
        for (int p = 0; p < NPART_; ++p) M = fmaxf(M, s_m[p]);

        const int d0 = lane * 2;
        const float2 vn = *(const float2*)(vnew + (size_t)bh * D_ + d0);
        const float wn = __expf(sc - M);   // new-key partial: m=sc, l=1
        float L  = wn;
        float a0 = wn * vn.x;
        float a1 = wn * vn.y;
        #pragma unroll
        for (int p = 0; p < NPART_; ++p) {
            const float w = __expf(s_m[p] - M);  // empty partial: exp(-inf)=0
            L  += w * s_l[p];
            a0 += w * s_o[p][d0];
            a1 += w * s_o[p][d0 + 1];
        }
        out[(size_t)bh * D_ + d0]     = a0 / L;
        out[(size_t)bh * D_ + d0 + 1] = a1 / L;
    }
}

extern "C" void kernel_launch(void* const* d_in, const int* in_sizes, int n_in,
                              void* d_out, int out_size, void* d_ws, size_t ws_size,
                              hipStream_t stream) {
    const float* q    = (const float*)d_in[0];
    const float* knew = (const float*)d_in[1];
    const float* vnew = (const float*)d_in[2];
    const float* ck   = (const float*)d_in[3];
    const float* cv   = (const float*)d_in[4];
    const int*   cpos = (const int*)d_in[5];
    float* out = (float*)d_out;

    attn_fused_kernel<<<BH_, NW_ * 64, 0, stream>>>(q, knew, vnew, ck, cv, cpos, out);
}